// Round 1
// baseline (114.745 us; speedup 1.0000x reference)
//
#include <hip/hip_runtime.h>
#include <hip/hip_bf16.h>

typedef __attribute__((ext_vector_type(8))) short bf16x8;
typedef __attribute__((ext_vector_type(4))) float f32x4;
typedef unsigned short u16;
typedef unsigned int u32;

#define NH 8
#define NN 4096
#define MM 4096
// D_IN=16, D_Q=D_V=32 hard-coded below

__device__ __forceinline__ u16 f2bf(float f) {
  u32 b = __float_as_uint(f);
  b += 0x7FFFu + ((b >> 16) & 1u);   // RNE to bf16
  return (u16)(b >> 16);
}

// ---------------- projections: q,k -> bf16 (scale folded into q) ----------------
__global__ __launch_bounds__(256) void proj_qk_kernel(
    const float* __restrict__ x, const float* __restrict__ y,
    const float* __restrict__ Wq, const float* __restrict__ bq,
    const float* __restrict__ Wk, const float* __restrict__ bk,
    u16* __restrict__ qs, u16* __restrict__ ks)
{
  int idx = blockIdx.x * 256 + threadIdx.x;   // 65536 total
  int t = idx >> 15;                          // 0 = q (from x), 1 = k (from y)
  int h = (idx >> 12) & 7;
  int row = idx & 4095;
  const float* src = (t ? y : x) + row * 16;
  const float* W = (t ? Wk : Wq) + (h << 9);
  const float* b = (t ? bk : bq) + (h << 5);
  const float scale = t ? 1.0f : 0.17677669529663687f;  // 1/sqrt(32)
  float r[16];
#pragma unroll
  for (int i = 0; i < 16; ++i) r[i] = src[i];
  u16* out = (t ? ks : qs) + (idx & 32767) * 32;        // (h*4096+row)*32
#pragma unroll
  for (int j = 0; j < 32; ++j) {
    float a = b[j];
#pragma unroll
    for (int i = 0; i < 16; ++i) a = fmaf(r[i], W[i * 32 + j], a);
    out[j] = f2bf(a * scale);
  }
}

// ---------------- projection: v -> bf16, transposed to vT[h][dv][m] ----------------
__global__ __launch_bounds__(256) void proj_v_kernel(
    const float* __restrict__ y, const float* __restrict__ Wv,
    const float* __restrict__ bv, u16* __restrict__ vT)
{
  __shared__ u16 sv[256][33];
  int h = blockIdx.x >> 4;
  int kb = (blockIdx.x & 15) << 8;   // 256 keys per block
  int tid = threadIdx.x;
  const float* src = y + (kb + tid) * 16;
  const float* W = Wv + (h << 9);
  const float* b = bv + (h << 5);
  float r[16];
#pragma unroll
  for (int i = 0; i < 16; ++i) r[i] = src[i];
#pragma unroll
  for (int j = 0; j < 32; ++j) {
    float a = b[j];
#pragma unroll
    for (int i = 0; i < 16; ++i) a = fmaf(r[i], W[i * 32 + j], a);
    sv[tid][j] = f2bf(a);
  }
  __syncthreads();
  int dv = tid >> 3;
  int c = (tid & 7) << 5;            // 32-key chunk
  u16* dst = vT + (((h << 5) + dv) << 12) + kb + c;
#pragma unroll
  for (int q = 0; q < 4; ++q) {
    uint4 w;
    w.x = (u32)sv[c + q * 8 + 0][dv] | ((u32)sv[c + q * 8 + 1][dv] << 16);
    w.y = (u32)sv[c + q * 8 + 2][dv] | ((u32)sv[c + q * 8 + 3][dv] << 16);
    w.z = (u32)sv[c + q * 8 + 4][dv] | ((u32)sv[c + q * 8 + 5][dv] << 16);
    w.w = (u32)sv[c + q * 8 + 6][dv] | ((u32)sv[c + q * 8 + 7][dv] << 16);
    *(uint4*)(dst + q * 8) = w;
  }
}

// ---------------- flash attention: S^T = K Q^T, O^T = V^T P^T ----------------
__global__ __launch_bounds__(256) void flash_kernel(
    const u16* __restrict__ qs, const u16* __restrict__ ksrc,
    const u16* __restrict__ vT, float* __restrict__ concat)
{
  __shared__ u16 sK[64 * 36];    // [64 keys][32 dq] padded to 36
  __shared__ u16 sVT[32 * 72];   // [32 dv][64 keys] padded to 72
  const int h = blockIdx.y;
  const int qt = blockIdx.x;
  const int tid = threadIdx.x;
  const int wv = tid >> 6;
  const int lane = tid & 63;
  const int d = lane & 15;       // qrow-in-16 (B col / C col); also A-row index
  const int g = lane >> 4;       // lane group
  const int qrow = (qt << 6) + (wv << 4) + d;

  // Q fragment: lane holds q[qrow][k] for k = 16*(j>>2) + 4g + (j&3)
  const u16* qp = qs + (((h << 12) + qrow) << 5) + (g << 2);
  union { uint2 q2[2]; bf16x8 v; } qf;
  qf.q2[0] = *(const uint2*)qp;
  qf.q2[1] = *(const uint2*)(qp + 16);

  float mrun = -1e30f, lsum = 0.f;
  f32x4 acc0 = {0.f, 0.f, 0.f, 0.f};
  f32x4 acc1 = {0.f, 0.f, 0.f, 0.f};
  const f32x4 zero = {0.f, 0.f, 0.f, 0.f};

  for (int kt = 0; kt < MM; kt += 64) {
    __syncthreads();
    // stage K tile (contiguous 4KB in global) into padded LDS
    {
      uint4 w = *(const uint4*)(ksrc + (((h << 12) + kt) << 5) + (tid << 3));
      u16* dk = sK + (tid >> 2) * 36 + ((tid & 3) << 3);
      *(uint2*)dk = make_uint2(w.x, w.y);
      *(uint2*)(dk + 4) = make_uint2(w.z, w.w);
    }
    // stage V^T tile: 32 dv rows x 128B each
    {
      uint4 w = *(const uint4*)(vT + ((((h << 5) + (tid >> 3)) << 12) + kt + ((tid & 7) << 3)));
      u16* dvp = sVT + (tid >> 3) * 72 + ((tid & 7) << 3);
      *(uint4*)dvp = w;
    }
    __syncthreads();

    // S^T subtiles: D[key16][qrow], keys t*16 + 4g + r per lane
    f32x4 s0, s1, s2, s3;
    {
      union { uint2 q2[2]; bf16x8 v; } af;
      const u16* kp = sK + d * 36 + (g << 2);
      af.q2[0] = *(const uint2*)kp;  af.q2[1] = *(const uint2*)(kp + 16);
      s0 = __builtin_amdgcn_mfma_f32_16x16x32_bf16(af.v, qf.v, zero, 0, 0, 0);
      kp += 16 * 36;
      af.q2[0] = *(const uint2*)kp;  af.q2[1] = *(const uint2*)(kp + 16);
      s1 = __builtin_amdgcn_mfma_f32_16x16x32_bf16(af.v, qf.v, zero, 0, 0, 0);
      kp += 16 * 36;
      af.q2[0] = *(const uint2*)kp;  af.q2[1] = *(const uint2*)(kp + 16);
      s2 = __builtin_amdgcn_mfma_f32_16x16x32_bf16(af.v, qf.v, zero, 0, 0, 0);
      kp += 16 * 36;
      af.q2[0] = *(const uint2*)kp;  af.q2[1] = *(const uint2*)(kp + 16);
      s3 = __builtin_amdgcn_mfma_f32_16x16x32_bf16(af.v, qf.v, zero, 0, 0, 0);
    }

    // online softmax over this tile's 64 keys (scale pre-folded into q)
    float p[16];
    p[0]=s0.x; p[1]=s0.y; p[2]=s0.z; p[3]=s0.w;
    p[4]=s1.x; p[5]=s1.y; p[6]=s1.z; p[7]=s1.w;
    p[8]=s2.x; p[9]=s2.y; p[10]=s2.z; p[11]=s2.w;
    p[12]=s3.x; p[13]=s3.y; p[14]=s3.z; p[15]=s3.w;
    float mx = p[0];
#pragma unroll
    for (int i = 1; i < 16; ++i) mx = fmaxf(mx, p[i]);
    mx = fmaxf(mx, __shfl_xor(mx, 16));
    mx = fmaxf(mx, __shfl_xor(mx, 32));
    const float mnew = fmaxf(mrun, mx);
    const float corr = __expf(mrun - mnew);
    mrun = mnew;
    float ls = 0.f;
#pragma unroll
    for (int i = 0; i < 16; ++i) { p[i] = __expf(p[i] - mnew); ls += p[i]; }
    ls += __shfl_xor(ls, 16);
    ls += __shfl_xor(ls, 32);
    lsum = lsum * corr + ls;
    acc0 *= corr;
    acc1 *= corr;

    // P^T fragments (lane-local): pb0 = keys 0..31, pb1 = keys 32..63
    union { u16 u[8]; bf16x8 v; } pb0, pb1;
#pragma unroll
    for (int j = 0; j < 8; ++j) { pb0.u[j] = f2bf(p[j]); pb1.u[j] = f2bf(p[8 + j]); }

    // O^T += V^T * P^T   (acc col = qrow = lane&15, row = dv-in-16 = 4g+r)
    {
      union { uint2 q2[2]; bf16x8 v; } af;
      const u16* vp = sVT + d * 72 + (g << 2);
      af.q2[0] = *(const uint2*)vp;        af.q2[1] = *(const uint2*)(vp + 16);
      acc0 = __builtin_amdgcn_mfma_f32_16x16x32_bf16(af.v, pb0.v, acc0, 0, 0, 0);
      af.q2[0] = *(const uint2*)(vp + 32); af.q2[1] = *(const uint2*)(vp + 48);
      acc0 = __builtin_amdgcn_mfma_f32_16x16x32_bf16(af.v, pb1.v, acc0, 0, 0, 0);
      vp += 16 * 72;
      af.q2[0] = *(const uint2*)vp;        af.q2[1] = *(const uint2*)(vp + 16);
      acc1 = __builtin_amdgcn_mfma_f32_16x16x32_bf16(af.v, pb0.v, acc1, 0, 0, 0);
      af.q2[0] = *(const uint2*)(vp + 32); af.q2[1] = *(const uint2*)(vp + 48);
      acc1 = __builtin_amdgcn_mfma_f32_16x16x32_bf16(af.v, pb1.v, acc1, 0, 0, 0);
    }
  }

  const float inv = 1.0f / lsum;
  float* cp = concat + (qrow << 8) + (h << 5) + (g << 2);
  *(float4*)cp        = make_float4(acc0.x * inv, acc0.y * inv, acc0.z * inv, acc0.w * inv);
  *(float4*)(cp + 16) = make_float4(acc1.x * inv, acc1.y * inv, acc1.z * inv, acc1.w * inv);
}

// ---------------- output projection: out = concat @ Wo + bo ----------------
__global__ __launch_bounds__(256) void out_gemm_kernel(
    const float* __restrict__ concat, const float* __restrict__ Wo,
    const float* __restrict__ bo, float* __restrict__ out)
{
  __shared__ float sWo[4096];
  int tid = threadIdx.x;
  for (int i = tid; i < 4096; i += 256) sWo[i] = Wo[i];
  __syncthreads();
  int idx = blockIdx.x * 256 + tid;
  int n = idx >> 4;
  int c = idx & 15;
  const float4* crow = (const float4*)(concat + (n << 8));
  float a = bo[c];
#pragma unroll 4
  for (int i4 = 0; i4 < 64; ++i4) {
    float4 cv = crow[i4];
    a = fmaf(cv.x, sWo[(i4 * 4 + 0) * 16 + c], a);
    a = fmaf(cv.y, sWo[(i4 * 4 + 1) * 16 + c], a);
    a = fmaf(cv.z, sWo[(i4 * 4 + 2) * 16 + c], a);
    a = fmaf(cv.w, sWo[(i4 * 4 + 3) * 16 + c], a);
  }
  out[idx] = a;
}

extern "C" void kernel_launch(void* const* d_in, const int* in_sizes, int n_in,
                              void* d_out, int out_size, void* d_ws, size_t ws_size,
                              hipStream_t stream) {
  const float* x  = (const float*)d_in[0];
  const float* y  = (const float*)d_in[1];
  const float* Wq = (const float*)d_in[2];
  const float* bq = (const float*)d_in[3];
  const float* Wk = (const float*)d_in[4];
  const float* bk = (const float*)d_in[5];
  const float* Wv = (const float*)d_in[6];
  const float* bv = (const float*)d_in[7];
  const float* Wo = (const float*)d_in[8];
  const float* bo = (const float*)d_in[9];
  float* out = (float*)d_out;

  u16* qs = (u16*)d_ws;                       // [8][4096][32] bf16  (2 MB)
  u16* ks = qs + (NH * NN * 32);              // [8][4096][32] bf16  (2 MB)
  u16* vT = ks + (NH * MM * 32);              // [8][32][4096] bf16  (2 MB)
  float* concat = (float*)(vT + (NH * MM * 32)); // [4096][256] f32  (4 MB)

  hipLaunchKernelGGL(proj_qk_kernel, dim3(256), dim3(256), 0, stream,
                     x, y, Wq, bq, Wk, bk, qs, ks);
  hipLaunchKernelGGL(proj_v_kernel, dim3(128), dim3(256), 0, stream, y, Wv, bv, vT);
  hipLaunchKernelGGL(flash_kernel, dim3(64, NH), dim3(256), 0, stream, qs, ks, vT, concat);
  hipLaunchKernelGGL(out_gemm_kernel, dim3(256), dim3(256), 0, stream, concat, Wo, bo, out);
}